// Round 1
// baseline (18.335 us; speedup 1.0000x reference)
//
#include <hip/hip_runtime.h>
#include <math.h>

#define NW 10
#define DIM 1024
#define NK 11   // popcount classes 0..10
#define NM 21   // polynomial orders 0..20

// ---------------------------------------------------------------------------
// Setup: compute A[w][m] = sum_{k+l=m} sum_i sign_w(i) * W_k[i] * W_l[i]
// where W_k = (fixed RY layer) * (CX ring permutation) * u_k,
// u_k = indicator of popcount==k. One block per m (21 blocks), 1024 threads
// (one per basis index).
// Wire w <-> bit position (9-w)  (wire 0 = MSB, torchquantum layout).
// ---------------------------------------------------------------------------
__global__ __launch_bounds__(1024) void qsetup(const float* __restrict__ ry,
                                               float* __restrict__ A) {
  const int idx = threadIdx.x;   // basis index 0..1023
  const int m   = blockIdx.x;    // polynomial order handled by this block

  __shared__ float W[NK][DIM];       // 45056 B
  __shared__ float rc[NW], rs[NW];
  __shared__ float part[16][NW];     // per-wave signed partials

  if (idx < NW) {
    float t = ry[idx] * 0.5f;
    rc[idx] = cosf(t);
    rs[idx] = sinf(t);
  }

  // CX ring permutation: psi_after[idx] = psi_before[G_0(G_1(...G_9(idx)))]
  // (gate w = CX(ctrl=w, tgt=(w+1)%10); evaluate innermost G_9 first).
  int j = idx;
#pragma unroll
  for (int w = NW - 1; w >= 0; --w) {
    const int tgt = (w + 1) % NW;
    const int cb  = (j >> (NW - 1 - w)) & 1;
    j ^= cb << (NW - 1 - tgt);
  }
  const int pc = __popc(j);

  // init all 11 k-vectors simultaneously (post-permutation image of u_k)
  float self[NK];
#pragma unroll
  for (int k = 0; k < NK; ++k) {
    self[k] = (pc == k) ? 1.0f : 0.0f;
    W[k][idx] = self[k];
  }
  __syncthreads();

  // fixed RY layer, applied to all 11 vectors at once (2 syncs per wire)
#pragma unroll
  for (int w = 0; w < NW; ++w) {
    const int mask = 1 << (NW - 1 - w);
    const float c = rc[w], s = rs[w];
    float partner[NK];
#pragma unroll
    for (int k = 0; k < NK; ++k) partner[k] = W[k][idx ^ mask];
    __syncthreads();
    const bool hi = (idx & mask) != 0;
#pragma unroll
    for (int k = 0; k < NK; ++k) {
      // new0 = c*a - s*b ; new1 = s*a + c*b  (a = bit0 elem, b = bit1 elem)
      float nv = hi ? fmaf(s, partner[k], c * self[k])
                    : fmaf(c, self[k], -s * partner[k]);
      self[k] = nv;
      W[k][idx] = nv;
    }
    __syncthreads();
  }

  // q_m(idx) = sum_{k+l=m} W_k[idx] * W_l[idx]   (ordered pairs)
  float q = 0.0f;
  {
    int k0 = m - (NK - 1); if (k0 < 0) k0 = 0;
    int k1 = m;            if (k1 > NK - 1) k1 = NK - 1;
    for (int k = k0; k <= k1; ++k) q += self[k] * self[m - k];
  }

  // Shared-prefix signed butterfly over lane bits 0..5 (wires 9..4).
  // After stage p: v = sum over bits<p ; d[p] = bit-p-signed sum over bits<=p.
  float v = q;
  float d[6];
#pragma unroll
  for (int p = 0; p < 6; ++p) {
    float o = __shfl_xor(v, 1 << p);
    d[p] = ((idx >> p) & 1) ? (o - v) : (v - o);
    v += o;
  }
#pragma unroll
  for (int p = 0; p < 6; ++p) {
#pragma unroll
    for (int pp = p + 1; pp < 6; ++pp) d[p] += __shfl_xor(d[p], 1 << pp);
  }

  const int lane = idx & 63;
  const int wv   = idx >> 6;   // wave id = idx bits 6..9 (wires 3..0)
  if (lane == 0) {
#pragma unroll
    for (int p = 0; p < 6; ++p) part[wv][9 - p] = d[p];     // wires 4..9
#pragma unroll
    for (int w = 0; w < 4; ++w)                              // wires 0..3
      part[wv][w] = ((wv >> (3 - w)) & 1) ? -v : v;
  }
  __syncthreads();

  if (idx < NW) {
    float acc = 0.0f;
#pragma unroll
    for (int vv = 0; vv < 16; ++vv) acc += part[vv][idx];
    A[idx * NM + m] = acc;
  }
}

// ---------------------------------------------------------------------------
// Main: per sample, exps_w = sum_m A[w][m] * c^(20-m) * s^m,
// c = cos(x/2), s = sin(x/2). 1 sample per thread.
// ---------------------------------------------------------------------------
__global__ __launch_bounds__(256) void qmain(const float* __restrict__ x,
                                             const float* __restrict__ A,
                                             float* __restrict__ out,
                                             int B) {
  __shared__ float sA[NW * NM];        // 210 coeffs, broadcast-read
  __shared__ float so[256 * (NW + 1)]; // staging, pad stride 11 (bank-safe)

  const int t = threadIdx.x;
  if (t < NW * NM) sA[t] = A[t];
  __syncthreads();

  const int b = blockIdx.x * 256 + t;
  float o[NW];
  if (b < B) {
    const float th = x[b] * 0.5f;
    float s, c;
    sincosf(th, &s, &c);

    float cpw[NM], spw[NM];
    cpw[0] = 1.0f; spw[0] = 1.0f;
#pragma unroll
    for (int i = 1; i < NM; ++i) { cpw[i] = cpw[i - 1] * c; spw[i] = spw[i - 1] * s; }
    float P[NM];
#pragma unroll
    for (int mm = 0; mm < NM; ++mm) P[mm] = cpw[20 - mm] * spw[mm];

#pragma unroll
    for (int w = 0; w < NW; ++w) {
      float acc = 0.0f;
#pragma unroll
      for (int mm = 0; mm < NM; ++mm) acc = fmaf(sA[w * NM + mm], P[mm], acc);
      o[w] = acc;
    }
  } else {
#pragma unroll
    for (int w = 0; w < NW; ++w) o[w] = 0.0f;
  }

#pragma unroll
  for (int w = 0; w < NW; ++w) so[t * (NW + 1) + w] = o[w];
  __syncthreads();

  // coalesced write-out: block covers out[bid*2560 .. bid*2560+2559]
  const long long base = (long long)blockIdx.x * 256 * NW;
#pragma unroll
  for (int jj = 0; jj < NW; ++jj) {
    const int i  = jj * 256 + t;        // 0..2559
    const int bl = i / NW;              // local sample
    const int w  = i % NW;              // wire
    const long long gi = base + i;
    if (gi < (long long)B * NW) out[gi] = so[bl * (NW + 1) + w];
  }
}

extern "C" void kernel_launch(void* const* d_in, const int* in_sizes, int n_in,
                              void* d_out, int out_size, void* d_ws, size_t ws_size,
                              hipStream_t stream) {
  const float* x  = (const float*)d_in[0];   // 65536 angles
  const float* ry = (const float*)d_in[1];   // 10 fixed RY params
  float* out = (float*)d_out;                // 65536 x 10, fp32
  float* A   = (float*)d_ws;                 // 210 coeffs (840 B scratch)

  const int B = in_sizes[0];

  qsetup<<<NM, 1024, 0, stream>>>(ry, A);
  const int blocks = (B + 255) / 256;
  qmain<<<blocks, 256, 0, stream>>>(x, A, out, B);
}

// Round 2
// 9.895 us; speedup vs baseline: 1.8530x; 1.8530x over previous
//
#include <hip/hip_runtime.h>
#include <math.h>

#define NW 10
#define DIM 1024
#define NM 21   // polynomial orders 0..20 in c^(20-m) s^m

// ---------------------------------------------------------------------------
// Compile-time tables.
// P(j): CX-ring permutation preimage (psi_after[j] = psi_before[P(j)]),
//       gates CX(w, (w+1)%10) applied w=0..9; wire w <-> bit (9-w).
// k(j) = popcount(P(j)).
// D[w][m] = sum_{j: 2k(j)==m} (-1)^{bit_w(j)}      (diagonal term)
// X[w][m] = #{j: k(j) + k(j^e_w) == m}             (cross term)
// exps_w  = cos(ry_w) * sum_m D[w][m] P_m  -  sin(ry_w) * sum_m X[w][m] P_m
// ---------------------------------------------------------------------------
struct Tables { int D[NW][NM]; int X[NW][NM]; };

constexpr Tables gen_tables() {
  Tables t{};
  int k[DIM] = {};
  for (int j = 0; j < DIM; ++j) {
    int p = j;
    for (int w = NW - 1; w >= 0; --w) {
      const int tgt = (w + 1) % NW;
      const int cb  = (p >> (NW - 1 - w)) & 1;
      p ^= cb << (NW - 1 - tgt);
    }
    int pc = 0;
    for (int b = 0; b < NW; ++b) pc += (p >> b) & 1;
    k[j] = pc;
  }
  for (int w = 0; w < NW; ++w) {
    const int ew = 1 << (NW - 1 - w);
    for (int j = 0; j < DIM; ++j) {
      const int bw = (j >> (NW - 1 - w)) & 1;
      t.D[w][2 * k[j]] += bw ? -1 : 1;
      t.X[w][k[j] + k[j ^ ew]] += 1;
    }
  }
  return t;
}

constexpr Tables TAB = gen_tables();

// ---------------------------------------------------------------------------
// Single fused kernel: 1 sample per thread.
// ---------------------------------------------------------------------------
__global__ __launch_bounds__(256) void qmain(const float* __restrict__ x,
                                             const float* __restrict__ ry,
                                             float* __restrict__ out,
                                             int B) {
  __shared__ float sA[NW * NM];        // 210 coefficients
  __shared__ float so[256 * (NW + 1)]; // output staging, stride 11 (bank-safe)

  const int t = threadIdx.x;
  if (t < NW * NM) {
    const int w = t / NM, m = t % NM;
    const float r = ry[w];
    sA[t] = cosf(r) * (float)TAB.D[w][m] - sinf(r) * (float)TAB.X[w][m];
  }
  __syncthreads();

  const int b = blockIdx.x * 256 + t;
  float o[NW];
  if (b < B) {
    const float th = x[b] * 0.5f;
    float s, c;
    sincosf(th, &s, &c);

    float cpw[NM], spw[NM];
    cpw[0] = 1.0f; spw[0] = 1.0f;
#pragma unroll
    for (int i = 1; i < NM; ++i) { cpw[i] = cpw[i - 1] * c; spw[i] = spw[i - 1] * s; }
    float P[NM];
#pragma unroll
    for (int mm = 0; mm < NM; ++mm) P[mm] = cpw[20 - mm] * spw[mm];

#pragma unroll
    for (int w = 0; w < NW; ++w) {
      float acc = 0.0f;
#pragma unroll
      for (int mm = 0; mm < NM; ++mm) acc = fmaf(sA[w * NM + mm], P[mm], acc);
      o[w] = acc;
    }
  } else {
#pragma unroll
    for (int w = 0; w < NW; ++w) o[w] = 0.0f;
  }

#pragma unroll
  for (int w = 0; w < NW; ++w) so[t * (NW + 1) + w] = o[w];
  __syncthreads();

  // coalesced write-out: block covers out[bid*2560 .. bid*2560+2559]
  const long long base = (long long)blockIdx.x * 256 * NW;
#pragma unroll
  for (int jj = 0; jj < NW; ++jj) {
    const int i  = jj * 256 + t;        // 0..2559
    const int bl = i / NW;              // local sample
    const int w  = i % NW;              // wire
    const long long gi = base + i;
    if (gi < (long long)B * NW) out[gi] = so[bl * (NW + 1) + w];
  }
}

extern "C" void kernel_launch(void* const* d_in, const int* in_sizes, int n_in,
                              void* d_out, int out_size, void* d_ws, size_t ws_size,
                              hipStream_t stream) {
  const float* x  = (const float*)d_in[0];   // 65536 angles
  const float* ry = (const float*)d_in[1];   // 10 fixed RY params
  float* out = (float*)d_out;                // 65536 x 10, fp32

  const int B = in_sizes[0];
  const int blocks = (B + 255) / 256;
  qmain<<<blocks, 256, 0, stream>>>(x, ry, out, B);
}